// Round 1
// baseline (218.754 us; speedup 1.0000x reference)
//
#include <hip/hip_runtime.h>
#include <hip/hip_bf16.h>
#include <stdint.h>

typedef unsigned short u16;
typedef __bf16 bf16x8 __attribute__((ext_vector_type(8)));
typedef float f32x4 __attribute__((ext_vector_type(4)));

#define MFMA16(a, b, c) __builtin_amdgcn_mfma_f32_16x16x32_bf16((a), (b), (c), 0, 0, 0)

#define GLOAD16(g, l)                                                        \
  __builtin_amdgcn_global_load_lds(                                          \
      (const __attribute__((address_space(1))) void*)(g),                    \
      (__attribute__((address_space(3))) void*)(l), 16, 0, 0)

static __device__ __forceinline__ u16 f2bf(float f) {
  union { float f; uint32_t u; } v;
  v.f = f;
  uint32_t u = v.u;
  return (u16)((u + 0x7FFFu + ((u >> 16) & 1u)) >> 16);  // RNE
}

// ---- workspace layout (u16 elements) ----
// featT: [8][98][98][256] bf16, zero halo
#define FEATT_ELEMS (8u * 98u * 98u * 256u)   // 19,668,992
#define W1T_OFF     FEATT_ELEMS               // [oc][tap][cin] bf16: 256*2304
#define W1T_ELEMS   (256u * 2304u)
#define W2B_OFF     (W1T_OFF + W1T_ELEMS)     // [576][256] bf16
#define W2B_ELEMS   (576u * 256u)
#define X_OFF       (W2B_OFF + W2B_ELEMS)     // [73728][256] bf16

// ---------------- prep: feat NCHW f32 -> featT [b][h+1][w+1][c] bf16 -------------
__global__ __launch_bounds__(256) void prep_featT(const float* __restrict__ feat,
                                                  u16* __restrict__ featT) {
  const int pt = blockIdx.x, ct = blockIdx.y, b = blockIdx.z;
  const int p0 = pt * 64, c0 = ct * 64;
  __shared__ float tile[64][65];
  const int t = threadIdx.x;
  const int pj = t & 63, ci0 = t >> 6;
#pragma unroll
  for (int r = 0; r < 16; ++r) {
    int ci = r * 4 + ci0;
    tile[ci][pj] = feat[(b * 256 + c0 + ci) * 9216 + p0 + pj];
  }
  __syncthreads();
  const int pl = t >> 2, cc0 = (t & 3) * 16;
  const int pix = p0 + pl;
  const int h = pix / 96, w = pix % 96;
  uint32_t u[8];
#pragma unroll
  for (int i = 0; i < 8; ++i) {
    u16 lo = f2bf(tile[cc0 + 2 * i][pl]);
    u16 hi = f2bf(tile[cc0 + 2 * i + 1][pl]);
    u[i] = (uint32_t)lo | ((uint32_t)hi << 16);
  }
  uint4* dst = (uint4*)(featT + (size_t)((b * 98 + h + 1) * 98 + (w + 1)) * 256 + c0 + cc0);
  dst[0] = make_uint4(u[0], u[1], u[2], u[3]);
  dst[1] = make_uint4(u[4], u[5], u[6], u[7]);
}

// ---------------- prep: weights -> bf16 (w1 reordered to [oc][tap][cin]) ---------
__global__ __launch_bounds__(256) void prep_w(const float* __restrict__ w1,
                                              const float* __restrict__ w2,
                                              u16* __restrict__ w1t,
                                              u16* __restrict__ w2b) {
  int i = blockIdx.x * 256 + threadIdx.x;
  if (i < 589824) {
    int oc = i / 2304, r = i % 2304;
    int tap = r >> 8, cin = r & 255;
    w1t[i] = f2bf(w1[(oc * 256 + cin) * 9 + tap]);
  } else {
    int j = i - 589824;
    if (j < 147456) w2b[j] = f2bf(w2[j]);
  }
}

// ---------------- GEMM1: x[pix][oc] = conv3x3(feat) + b1, relu, bf16 -------------
// M=73728 (pix), N=256 (oc), K=2304 (tap*256+cin). 128x128 tile, BK=64, 4 waves.
__global__ __launch_bounds__(256, 2) void gemm1(const u16* __restrict__ featT,
                                                const u16* __restrict__ w1t,
                                                const float* __restrict__ b1,
                                                u16* __restrict__ xout) {
  __shared__ __align__(16) u16 sA[2][128 * 64];
  __shared__ __align__(16) u16 sB[2][128 * 64];
  __shared__ float sb1[128];

  const int t = threadIdx.x;
  const int wave = t >> 6, lane = t & 63;
  const int nt = blockIdx.x & 1, mt = blockIdx.x >> 1;
  const int b = mt / 72;
  const int ip0 = (mt % 72) * 128;  // image-local pixel base
  const int oc0 = nt * 128;

  if (t < 128) sb1[t] = b1[oc0 + t];

  // per-thread staging bases (row = LDS row this lane covers; chunk src-swizzled)
  const u16* aBase[4];
  const u16* bBase[4];
#pragma unroll
  for (int r = 0; r < 4; ++r) {
    int row = (wave * 4 + r) * 8 + (lane >> 3);  // 0..127
    int chunk = (lane & 7) ^ (row & 7);
    int ip = ip0 + row;
    int h = ip / 96, w = ip % 96;
    aBase[r] = featT + (size_t)((b * 98 + h + 1) * 98 + (w + 1)) * 256 + chunk * 8;
    bBase[r] = w1t + (size_t)(oc0 + row) * 2304 + chunk * 8;
  }

  auto stage = [&](int kt, int bufi) {
    int tap = kt >> 2;
    int dh = tap / 3 - 1, dw = tap % 3 - 1;
    int aoff = (dh * 98 + dw) * 256 + (kt & 3) * 64;
    int boff = kt * 64;
#pragma unroll
    for (int r = 0; r < 4; ++r) {
      GLOAD16(aBase[r] + aoff, &sA[bufi][(wave * 4 + r) * 512]);
      GLOAD16(bBase[r] + boff, &sB[bufi][(wave * 4 + r) * 512]);
    }
  };

  const int wm = wave >> 1, wn = wave & 1;
  // fragment LDS offsets (swizzled)
  int aoffs[4][2], boffs[4][2];
#pragma unroll
  for (int m = 0; m < 4; ++m) {
#pragma unroll
    for (int ki = 0; ki < 2; ++ki) {
      int kc = ki * 4 + (lane >> 4);
      int rowa = wm * 64 + m * 16 + (lane & 15);
      aoffs[m][ki] = rowa * 64 + ((kc ^ (rowa & 7)) * 8);
      int rowb = wn * 64 + m * 16 + (lane & 15);
      boffs[m][ki] = rowb * 64 + ((kc ^ (rowb & 7)) * 8);
    }
  }

  f32x4 acc[4][4];
#pragma unroll
  for (int m = 0; m < 4; ++m)
#pragma unroll
    for (int n = 0; n < 4; ++n) acc[m][n] = f32x4{0.f, 0.f, 0.f, 0.f};

  stage(0, 0);
  int buf = 0;
  for (int kt = 0; kt < 36; ++kt) {
    __syncthreads();
    if (kt < 35) stage(kt + 1, buf ^ 1);
#pragma unroll
    for (int ki = 0; ki < 2; ++ki) {
      bf16x8 av[4], bv[4];
#pragma unroll
      for (int m = 0; m < 4; ++m) av[m] = *(const bf16x8*)&sA[buf][aoffs[m][ki]];
#pragma unroll
      for (int n = 0; n < 4; ++n) bv[n] = *(const bf16x8*)&sB[buf][boffs[n][ki]];
#pragma unroll
      for (int m = 0; m < 4; ++m)
#pragma unroll
        for (int n = 0; n < 4; ++n) acc[m][n] = MFMA16(av[m], bv[n], acc[m][n]);
    }
    buf ^= 1;
  }

  // epilogue: bias + relu + bf16 store to x[pix][oc]
  const int pix0g = mt * 128;
#pragma unroll
  for (int m = 0; m < 4; ++m) {
    int pixl = wm * 64 + m * 16 + ((lane >> 4) << 2);
#pragma unroll
    for (int n = 0; n < 4; ++n) {
      int oc = wn * 64 + n * 16 + (lane & 15);
      float bias = sb1[oc];
      f32x4 v = acc[m][n];
#pragma unroll
      for (int j = 0; j < 4; ++j) {
        float val = v[j] + bias;
        val = val > 0.f ? val : 0.f;
        xout[(size_t)(pix0g + pixl + j) * 256 + oc0 + oc] = f2bf(val);
      }
    }
  }
}

// ------- GEMM2: mask = x @ w2^T (+b2), softmax over 9, combine flow, scatter -----
// Block: 128 pixels, 512 threads (8 waves x 16-pixel M-slices).
// Virtual N order per pq-chunk: n = k*16 + pql  (9 N-frags = 9 softmax taps, lane-local)
__global__ __launch_bounds__(512, 1) void gemm2(const u16* __restrict__ xws,
                                                const u16* __restrict__ w2b,
                                                const float* __restrict__ b2,
                                                const float* __restrict__ flow,
                                                float* __restrict__ out) {
  __shared__ __align__(16) u16 sX[128 * 256];     // 64 KB
  __shared__ __align__(16) u16 sB2[2][144 * 64];  // 36 KB
  __shared__ float sFlow[2][9][128];              // 9 KB
  __shared__ float sb2[576];

  const int t = threadIdx.x;
  const int wave = t >> 6, lane = t & 63;
  const int mt = blockIdx.x;
  const int b = mt / 72;
  const int ip0 = (mt % 72) * 128;

  // stage x tile (source-chunk swizzled so frag reads are conflict-free)
#pragma unroll
  for (int r = 0; r < 8; ++r) {
    int wr = r * 8 + wave;                 // 0..63
    int pix = wr * 2 + (lane >> 5);        // 0..127
    int cpos = lane & 31;
    const u16* src = xws + (size_t)(mt * 128 + pix) * 256 + ((cpos ^ (pix & 7)) * 8);
    GLOAD16(src, &sX[wr * 512]);
  }
  // flow-unfold tile: sFlow[c][k][p]
  for (int i = t; i < 2304; i += 512) {
    int c = i / 1152, rem = i % 1152;
    int k = rem >> 7, p = rem & 127;
    int ip = ip0 + p;
    int h = ip / 96, w = ip % 96;
    int hh = h + k / 3 - 1, ww = w + k % 3 - 1;
    float v = 0.f;
    if (hh >= 0 && hh < 96 && ww >= 0 && ww < 96)
      v = flow[((b * 2 + c) * 96 + hh) * 96 + ww];
    sFlow[c][k][p] = v;
  }
  for (int i = t; i < 576; i += 512) sb2[i] = b2[i];

  auto stageB = [&](int step, int bufi) {
    int chunkI = step >> 2, ks = step & 3;
#pragma unroll
    for (int r = 0; r < 3; ++r) {
      int wr = r * 8 + wave;
      if (wr < 18) {
        int row = wr * 8 + (lane >> 3);  // virtual n, 0..143
        int c = (row >> 4) * 64 + chunkI * 16 + (row & 15);
        const u16* src = w2b + (size_t)c * 256 + ks * 64 + (((lane & 7) ^ (row & 7)) * 8);
        GLOAD16(src, &sB2[bufi][wr * 512]);
      }
    }
  };

  stageB(0, 0);
  int buf = 0;
  f32x4 acc[9];
#pragma unroll
  for (int nf = 0; nf < 9; ++nf) acc[nf] = f32x4{0.f, 0.f, 0.f, 0.f};
  const int pixl = wave * 16 + (lane & 15);

  for (int step = 0; step < 16; ++step) {
    __syncthreads();
    if (step < 15) stageB(step + 1, buf ^ 1);
    int ks = step & 3;
#pragma unroll
    for (int ki = 0; ki < 2; ++ki) {
      int c32 = ks * 8 + ki * 4 + (lane >> 4);
      bf16x8 a = *(const bf16x8*)&sX[pixl * 256 + ((c32 ^ (pixl & 7)) * 8)];
      int kc = ki * 4 + (lane >> 4);
#pragma unroll
      for (int nf = 0; nf < 9; ++nf) {
        int row = nf * 16 + (lane & 15);
        bf16x8 bv = *(const bf16x8*)&sB2[buf][row * 64 + ((kc ^ (row & 7)) * 8)];
        acc[nf] = MFMA16(a, bv, acc[nf]);
      }
    }
    if (ks == 3) {
      int chunkI = step >> 2;
      int pql = lane & 15;
      int p = chunkI * 2 + (pql >> 3), q = pql & 7;
#pragma unroll
      for (int j = 0; j < 4; ++j) {
        int pe = wave * 16 + ((lane >> 4) << 2) + j;
        float v[9], mx = -3.0e38f;
#pragma unroll
        for (int nf = 0; nf < 9; ++nf) {
          v[nf] = acc[nf][j] + sb2[nf * 64 + chunkI * 16 + pql];
          mx = fmaxf(mx, v[nf]);
        }
        float s = 0.f, fx = 0.f, fy = 0.f;
#pragma unroll
        for (int nf = 0; nf < 9; ++nf) {
          float e = __expf(v[nf] - mx);
          s += e;
          fx += e * sFlow[0][nf][pe];
          fy += e * sFlow[1][nf][pe];
        }
        float sc = 8.0f / s;
        int ip = ip0 + pe;
        int h = ip / 96, w = ip % 96;
        size_t o0 = ((size_t)(b * 2 + 0) * 768 + h * 8 + p) * 768 + w * 8 + q;
        size_t o1 = ((size_t)(b * 2 + 1) * 768 + h * 8 + p) * 768 + w * 8 + q;
        out[o0] = fx * sc;
        out[o1] = fy * sc;
      }
#pragma unroll
      for (int nf = 0; nf < 9; ++nf) acc[nf] = f32x4{0.f, 0.f, 0.f, 0.f};
    }
    buf ^= 1;
  }
}

extern "C" void kernel_launch(void* const* d_in, const int* in_sizes, int n_in,
                              void* d_out, int out_size, void* d_ws, size_t ws_size,
                              hipStream_t stream) {
  const float* flow = (const float*)d_in[0];
  const float* feat = (const float*)d_in[1];
  const float* w1 = (const float*)d_in[2];
  const float* b1 = (const float*)d_in[3];
  const float* w2 = (const float*)d_in[4];
  const float* b2 = (const float*)d_in[5];
  float* out = (float*)d_out;
  u16* ws = (u16*)d_ws;
  u16* featT = ws;
  u16* w1t = ws + W1T_OFF;
  u16* w2b = ws + W2B_OFF;
  u16* xws = ws + X_OFF;

  hipMemsetAsync(featT, 0, (size_t)FEATT_ELEMS * 2, stream);
  prep_featT<<<dim3(144, 4, 8), 256, 0, stream>>>(feat, featT);
  prep_w<<<2880, 256, 0, stream>>>(w1, w2, w1t, w2b);
  gemm1<<<1152, 256, 0, stream>>>(featT, w1t, b1, xws);
  gemm2<<<576, 512, 0, stream>>>(xws, w2b, b2, flow, out);
}